// Round 14
// baseline (1432.442 us; speedup 1.0000x reference)
//
#include <hip/hip_runtime.h>
#include <math.h>

typedef _Float16 f16;
typedef f16 f16x4 __attribute__((ext_vector_type(4)));
typedef f16 f16x8 __attribute__((ext_vector_type(8)));
typedef float f32x4 __attribute__((ext_vector_type(4)));

#define MFMA16(a, b, c) __builtin_amdgcn_mfma_f32_16x16x32_f16((a), (b), (c), 0, 0, 0)

typedef __attribute__((address_space(1))) const void glbv;
typedef __attribute__((address_space(3))) void ldsv;
#define GLD16(g, l) __builtin_amdgcn_global_load_lds((glbv*)(g), (ldsv*)(l), 16, 0, 0)

template <int N>
__device__ __forceinline__ void vm_wait() {
  asm volatile("s_waitcnt vmcnt(%0)" :: "i"(N) : "memory");
}

// stage one 2KB chunk: 16 rows x 64 f16 cols; 2 insts of 16B/lane.
// dest layout: inst j -> slot + j*512 f16 + lane*8 f16 (HW adds lane*16B).
__device__ __forceinline__ void issue_chunk(const f16* src, f16* slot) {
  GLD16(src, slot);
  GLD16(src + 32, slot + 512);
}

__device__ __forceinline__ f16x8 cfrag(const f16* slot, int j, int lane) {
  return *(const f16x8*)(slot + j * 512 + lane * 8);
}

// 3-deep per-wave pipeline over NCH chunks (wave-private slots: no barriers).
template <int NCH, class SRC, class CONS>
__device__ __forceinline__ void pipe3(SRC src, CONS cons, f16* s0, f16* s1, f16* s2) {
  issue_chunk(src(0), s0);
  if (NCH > 1) issue_chunk(src(1), s1);
#pragma unroll
  for (int ck = 0; ck < NCH; ++ck) {
    f16* cur = (ck % 3 == 0) ? s0 : (ck % 3 == 1 ? s1 : s2);
    if (ck + 2 < NCH) {
      f16* nxt = ((ck + 2) % 3 == 0) ? s0 : ((ck + 2) % 3 == 1 ? s1 : s2);
      issue_chunk(src(ck + 2), nxt);
      vm_wait<4>();
    } else if (ck + 1 < NCH) {
      vm_wait<2>();
    } else {
      vm_wait<0>();
    }
    cons(ck, cur);
  }
}

// ---------------------------------------------------------------------------
// ws layout (bytes): identical to R13.
// ---------------------------------------------------------------------------
struct PackArgs {
  const float *t_Wih, *t_Whh, *t_b, *a_Wih, *a_Whh, *a_b, *v_Wih, *v_Whh, *v_b;
  const float *aW1, *aW2, *bW1, *bW2, *g1W1, *g2W1, *g1W2, *g2W2, *oW1;
  f16 *Wg_t, *Wg_a, *Wg_v, *W_a1, *W_a2, *W_b1, *W_b2, *W_g1, *W_g2, *W_o1;
  float *bg;
};

__global__ __launch_bounds__(256) void pack_w(PackArgs p) {
  int idx = blockIdx.x * 256 + threadIdx.x;
  if (idx < 229376) {  // Wg_t [512][448]
    int n = idx / 448, k = idx % 448;
    int srow = (n & 3) * 128 + (n >> 2);
    float v = (k < 300) ? p.t_Wih[srow * 300 + k]
                        : ((k >= 320) ? p.t_Whh[srow * 128 + k - 320] : 0.f);
    p.Wg_t[idx] = (f16)v; return;
  }
  idx -= 229376;
  if (idx < 40960) {  // Wg_a [256][160]
    int n = idx / 160, k = idx % 160;
    int srow = (n & 3) * 64 + (n >> 2);
    float v = (k < 81) ? p.a_Wih[srow * 81 + k]
                       : ((k >= 96) ? p.a_Whh[srow * 64 + k - 96] : 0.f);
    p.Wg_a[idx] = (f16)v; return;
  }
  idx -= 40960;
  if (idx < 114688) {  // Wg_v [256][448]
    int n = idx / 448, k = idx % 448;
    int srow = (n & 3) * 64 + (n >> 2);
    float v = (k < 371) ? p.v_Wih[srow * 371 + k]
                        : ((k >= 384) ? p.v_Whh[srow * 64 + k - 384] : 0.f);
    p.Wg_v[idx] = (f16)v; return;
  }
  idx -= 114688;
  if (idx < 65536) { p.W_a1[idx] = (f16)p.aW1[idx]; return; }
  idx -= 65536;
  if (idx < 65536) { p.W_a2[idx] = (f16)p.aW2[idx]; return; }
  idx -= 65536;
  if (idx < 65536) { p.W_b1[idx] = (f16)p.bW1[idx]; return; }
  idx -= 65536;
  if (idx < 32768) { p.W_b2[idx] = (f16)p.bW2[idx]; return; }
  idx -= 32768;
  if (idx < 196608) {  // W_g1 [256][768]
    int n = idx / 768;
    p.W_g1[idx] = (f16)((n < 128) ? p.g1W1[idx] : p.g2W1[idx - 98304]);
    return;
  }
  idx -= 196608;
  if (idx < 65536) {  // W_g2 [512][128]
    int n = idx / 128;
    p.W_g2[idx] = (f16)((n < 256) ? p.g1W2[idx] : p.g2W2[idx - 32768]);
    return;
  }
  idx -= 65536;
  if (idx < 65536) { p.W_o1[idx] = (f16)p.oW1[idx]; return; }
  idx -= 65536;
  if (idx < 1024) {
    int n = idx;
    float v;
    if (n < 512)      v = p.t_b[(n & 3) * 128 + (n >> 2)];
    else if (n < 768) { int m = n - 512; v = p.a_b[(m & 3) * 64 + (m >> 2)]; }
    else              { int m = n - 768; v = p.v_b[(m & 3) * 64 + (m >> 2)]; }
    p.bg[n] = v;
  }
}

// ===========================================================================
// zx GEMM (unchanged from R13)
// ===========================================================================
struct ZxArgs { const float* x; const f16 *Wg_t, *Wg_a, *Wg_v; f16* zx; int t0; };

template <int KS, int KP, int XOFF>
__device__ __forceinline__ void zx_wave(const f16* __restrict__ Wg, int nc0, int n0g,
                                        const f16 (*Xs)[808], f16* __restrict__ zx,
                                        int mloc, int l15, int lg, int kst) {
#pragma unroll 1
  for (int half = 0; half < 2; ++half) {
    f32x4 acc[8];
#pragma unroll
    for (int j = 0; j < 8; ++j) acc[j] = (f32x4){0.f, 0.f, 0.f, 0.f};
#pragma unroll 1
    for (int kk = 0; kk < KS; ++kk) {
      int ks = kk + kst; if (ks >= KS) ks -= KS;
      f16x8 w[4];
#pragma unroll
      for (int i = 0; i < 4; ++i)
        w[i] = *(const f16x8*)(Wg + (size_t)(nc0 + 64 * half + 16 * i + l15) * KP + 32 * ks + 8 * lg);
      f16x8 a0 = *(const f16x8*)(&Xs[l15][XOFF + 32 * ks + 8 * lg]);
      f16x8 a1 = *(const f16x8*)(&Xs[16 + l15][XOFF + 32 * ks + 8 * lg]);
#pragma unroll
      for (int i = 0; i < 4; ++i) {
        acc[i] = MFMA16(a0, w[i], acc[i]);
        acc[4 + i] = MFMA16(a1, w[i], acc[4 + i]);
      }
    }
#pragma unroll
    for (int mt = 0; mt < 2; ++mt)
#pragma unroll
      for (int i = 0; i < 4; ++i) {
        int ng = n0g + 64 * half + 16 * i + l15;
#pragma unroll
        for (int q = 0; q < 4; ++q)
          zx[(size_t)(mloc + mt * 16 + 4 * lg + q) * 1024 + ng] = (f16)acc[mt * 4 + i][q];
      }
  }
}

__global__ __launch_bounds__(512, 2) void gemm_zx(ZxArgs z) {
  __shared__ f16 Xs[32][808];
  const int tid = threadIdx.x, wid = tid >> 6, lane = tid & 63, l15 = lane & 15, lg = lane >> 4;
  const int mloc = blockIdx.x * 32;
  {
    int r = tid >> 4;
    const float* xr = z.x + ((size_t)z.t0 * 4096 + mloc + r) * 752;
    for (int c = tid & 15; c < 800; c += 16) {
      float v;
      if (c < 320)      v = (c < 300) ? xr[c] : 0.f;
      else if (c < 416) { int s = c - 320; v = (s < 81) ? xr[300 + s] : 0.f; }
      else              { int s = c - 416; v = (s < 371) ? xr[381 + s] : 0.f; }
      Xs[r][c] = (f16)v;
    }
  }
  __syncthreads();
  if (wid < 4)
    zx_wave<10, 448, 0>(z.Wg_t, 128 * wid, 128 * wid, Xs, z.zx, mloc, l15, lg,
                        (int)(blockIdx.x % 10u));
  else if (wid < 6)
    zx_wave<3, 160, 320>(z.Wg_a, 128 * (wid - 4), 512 + 128 * (wid - 4), Xs, z.zx, mloc, l15, lg,
                         (int)(blockIdx.x % 3u));
  else
    zx_wave<12, 448, 416>(z.Wg_v, 128 * (wid - 6), 768 + 128 * (wid - 6), Xs, z.zx, mloc, l15, lg,
                          (int)(blockIdx.x % 12u));
}

// ===========================================================================
// Recurrent kernel — all weight reads via global_load_lds staging pipelines.
// ===========================================================================
struct MainArgs {
  const float *x_p, *c_t, *c_a, *c_v, *mem0;
  const f16 *Wg_t, *Wg_a, *Wg_v, *W_a1, *W_a2, *W_b1, *W_b2, *W_g1, *W_g2, *W_o1;
  const float *bg, *a1b1, *a1b2, *a2b1, *a2b2, *g1b1, *g1b2, *g2b1, *g2b2, *ob1, *oW2, *ob2;
  f16 *Hst; float *Cst, *Mst; const f16 *zx;
  float *out;
};

__device__ __forceinline__ float sigm(float x) {
  return __builtin_amdgcn_rcpf(1.f + __expf(-x));
}
__device__ __forceinline__ float ftanh(float x) {
  float t = __expf(-2.f * fabsf(x));
  float r = (1.f - t) * __builtin_amdgcn_rcpf(1.f + t);
  return copysignf(r, x);
}

__device__ __forceinline__ void gate_epi(const f32x4 acc, f16x4 z, float4 b,
                                         int nloc, int cub, int l15, int lg,
                                         f16 (*h16)[264], float (*cS)[260],
                                         f16 (*bufA)[808]) {
  float gi = sigm(acc[0] + (float)z[0] + b.x);
  float gf = sigm(acc[1] + (float)z[1] + b.y);
  float gg = ftanh(acc[2] + (float)z[2] + b.z);
  float go = sigm(acc[3] + (float)z[3] + b.w);
  int cu = cub + (nloc >> 2) + lg;
  float cold = cS[l15][cu];
  float cnew = gf * cold + gi * gg;
  cS[l15][cu] = cnew;
  h16[l15][cu] = (f16)(go * ftanh(cnew));
  bufA[l15][cu] = (f16)cold;        // c_star = [pre_c | cur_c]
  bufA[l15][256 + cu] = (f16)cnew;
}

// VGPR-path tile for the once-per-launch output head
template <int KS, int LDA>
__device__ __forceinline__ f32x4 fc_tileB(const f16 (*Asrc)[LDA], int acol,
                                          const f16* Wrow, int l15, int lg) {
  f32x4 acc = {0.f, 0.f, 0.f, 0.f};
  constexpr int GB = (KS < 8) ? KS : 8;
  constexpr int G = (KS + GB - 1) / GB;
#pragma unroll
  for (int g = 0; g < G; ++g) {
    f16x8 w[GB];
#pragma unroll
    for (int j = 0; j < GB; ++j) w[j] = *(const f16x8*)(Wrow + 32 * (g * GB + j));
#pragma unroll
    for (int j = 0; j < GB; ++j) {
      f16x8 a = *(const f16x8*)(&Asrc[l15][acol + 8 * lg + 32 * (g * GB + j)]);
      acc = MFMA16(a, w[j], acc);
    }
  }
  return acc;
}

__global__ __launch_bounds__(512, 2) void fused_seq(MainArgs A, int cs,
                                                    int first, int last) {
  __shared__ f16  h16[16][264];
  __shared__ float cS[16][260];
  __shared__ float mS[16][260];
  __shared__ f16  bufA[16][808];    // cstar/attended (0:512) | m fp16 (512:768)
  __shared__ f16  hid16[16][264];
  __shared__ float ovl[16][516];    // zf (f32 logits)  UNION  ghid16 (f16) — disjoint live ranges
  __shared__ f16  stg[8][3][1024];  // per-wave 3 x 2KB staging slots

  float (*zf)[516] = ovl;
  f16 (*ghid16)[264] = (f16 (*)[264])ovl;

  const int tid = threadIdx.x;
  const int wid = tid >> 6, lane = tid & 63, l15 = lane & 15, lg = lane >> 4;
  const int r0 = blockIdx.x * 16;
  const int rot = blockIdx.x & 7;

  const int gtw = (wid + rot) & 3;
  const int gaw = (wid - 4 + rot) & 1;
  const int gvw = (wid - 6 + rot) & 1;
  const int rw8 = (wid + rot) & 7;

  f16* s0 = &stg[wid][0][0];
  f16* s1 = &stg[wid][1][0];
  f16* s2 = &stg[wid][2][0];

  // gate role (wave-uniform)
  int g_nc0, g_n0, g_cub, g_hb, g_KP, g_HOFF, g_KSH;
  const f16* g_W;
  if (wid < 4)      { g_nc0 = 128 * gtw; g_n0 = g_nc0;       g_cub = 0;   g_hb = 0;   g_KP = 448; g_HOFF = 320; g_KSH = 4; g_W = A.Wg_t; }
  else if (wid < 6) { g_nc0 = 128 * gaw; g_n0 = 512 + g_nc0; g_cub = 128; g_hb = 128; g_KP = 160; g_HOFF = 96;  g_KSH = 2; g_W = A.Wg_a; }
  else              { g_nc0 = 128 * gvw; g_n0 = 768 + g_nc0; g_cub = 192; g_hb = 192; g_KP = 448; g_HOFF = 384; g_KSH = 2; g_W = A.Wg_v; }

  // ---- preload all step-invariant biases (keeps vmcnt pipelines pure) ----
  float4 bb[8];
#pragma unroll
  for (int t = 0; t < 8; ++t) bb[t] = *(const float4*)&A.bg[g_n0 + 16 * t + 4 * lg];
  const float b_a1 = A.a1b1[16 * rw8 + l15];
  float ba2[4];
#pragma unroll
  for (int i = 0; i < 4; ++i) ba2[i] = A.a1b2[64 * rw8 + 16 * i + l15];
  const float b_b1 = A.a2b1[16 * rw8 + l15];
  float gb[2];
#pragma unroll
  for (int i = 0; i < 2; ++i) {
    int nn = 16 * (2 * rw8 + i) + l15;
    gb[i] = (nn < 128) ? A.g1b1[nn] : A.g2b1[nn - 128];
  }
  float bB2[2], bG1[2], bG2[2];
#pragma unroll
  for (int i = 0; i < 2; ++i) {
    int n = 32 * rw8 + 16 * i + l15;
    bB2[i] = A.a2b2[n]; bG1[i] = A.g1b2[n]; bG2[i] = A.g2b2[n];
  }

  if (first) {
    for (int idx = tid; idx < 4096; idx += 512) {
      int r = idx >> 8, c = idx & 255, R = r0 + r;
      h16[r][c] = (f16)0.f;
      float cv = (c < 128) ? A.c_t[R * 128 + c]
                           : (c < 192 ? A.c_a[R * 64 + c - 128] : A.c_v[R * 64 + c - 192]);
      cS[r][c] = cv;
      mS[r][c] = A.mem0[R * 256 + c];
    }
  } else {
    for (int idx = tid; idx < 4096; idx += 512) {
      int r = idx >> 8, c = idx & 255;
      size_t g = (size_t)(r0 + r) * 256 + c;
      h16[r][c] = A.Hst[g];
      cS[r][c] = A.Cst[g];
      mS[r][c] = A.Mst[g];
    }
  }
  __syncthreads();

#pragma unroll 1
  for (int ts = 0; ts < cs; ++ts) {
    // ---- P0: h fragments + z quads (all VGPR loads drain at B0) ----------
    f16x8 ah[4];
#pragma unroll
    for (int k = 0; k < 4; ++k)
      if (k < g_KSH) ah[k] = *(const f16x8*)(&h16[l15][g_hb + 8 * lg + 32 * k]);
    const f16* zxr = A.zx + ((size_t)ts * 4096 + r0 + l15) * 1024;
    f16x4 zq[8];
#pragma unroll
    for (int t = 0; t < 8; ++t) zq[t] = *(const f16x4*)(zxr + g_n0 + 16 * t + 4 * lg);
    __syncthreads();  // B0

    // ---- gates: staged pipeline -------------------------------------------
    if (g_KSH == 4) {
      f32x4 accA = {0.f,0.f,0.f,0.f}, accB = {0.f,0.f,0.f,0.f};
      auto src = [&](int ck) -> const f16* {
        return g_W + (size_t)(g_nc0 + 16 * (ck >> 1) + l15) * 448 + 320 + 64 * (ck & 1) + 8 * lg;
      };
      auto cons = [&](int ck, f16* sl) {
        int T = (ck >> 1) & 1, c = ck & 1;
        f32x4& acc = T ? accB : accA;
        if (c == 0) acc = (f32x4){0.f, 0.f, 0.f, 0.f};
        acc = MFMA16(cfrag(sl, 0, lane), ah[2 * c + 0], acc);
        acc = MFMA16(cfrag(sl, 1, lane), ah[2 * c + 1], acc);
        if (c == 1) {
          int tk = ck >> 1;
          gate_epi(acc, zq[tk], bb[tk], g_nc0 + 16 * tk, g_cub, l15, lg, h16, cS, bufA);
        }
      };
      pipe3<16>(src, cons, s0, s1, s2);
    } else {
      auto src = [&](int ck) -> const f16* {
        return g_W + (size_t)(g_nc0 + 16 * ck + l15) * g_KP + g_HOFF + 8 * lg;
      };
      auto cons = [&](int ck, f16* sl) {
        f32x4 acc = (f32x4){0.f, 0.f, 0.f, 0.f};
        acc = MFMA16(cfrag(sl, 0, lane), ah[0], acc);
        acc = MFMA16(cfrag(sl, 1, lane), ah[1], acc);
        gate_epi(acc, zq[ck], bb[ck], g_nc0 + 16 * ck, g_cub, l15, lg, h16, cS, bufA);
      };
      pipe3<8>(src, cons, s0, s1, s2);
    }
    __syncthreads();  // B1: bufA complete

    // ---- attn1 L1: hid = relu(cstar @ W^T + b), staged --------------------
    {
      const f16* wbase = A.W_a1 + (size_t)(16 * rw8 + l15) * 512 + 8 * lg;
      f32x4 acc = (f32x4){0.f, 0.f, 0.f, 0.f};
      auto src = [&](int ck) -> const f16* { return wbase + 64 * ck; };
      auto cons = [&](int ck, f16* sl) {
#pragma unroll
        for (int j = 0; j < 2; ++j) {
          f16x8 a = *(const f16x8*)(&bufA[l15][8 * lg + 32 * (2 * ck + j)]);
          acc = MFMA16(a, cfrag(sl, j, lane), acc);
        }
      };
      pipe3<8>(src, cons, s0, s1, s2);
      int n = 16 * rw8;
#pragma unroll
      for (int q = 0; q < 4; ++q) hid16[lg * 4 + q][n + l15] = (f16)fmaxf(acc[q] + b_a1, 0.f);
    }
    __syncthreads();  // B2

    // ---- attn1 L2: logits, staged -----------------------------------------
    {
      f32x4 acc = (f32x4){0.f, 0.f, 0.f, 0.f};
      auto src = [&](int ck) -> const f16* {
        return A.W_a2 + (size_t)(64 * rw8 + 16 * (ck >> 1) + l15) * 128 + 64 * (ck & 1) + 8 * lg;
      };
      auto cons = [&](int ck, f16* sl) {
        int i = ck >> 1, c = ck & 1;
        if (c == 0) acc = (f32x4){0.f, 0.f, 0.f, 0.f};
#pragma unroll
        for (int j = 0; j < 2; ++j) {
          f16x8 a = *(const f16x8*)(&hid16[l15][8 * lg + 32 * (2 * c + j)]);
          acc = MFMA16(a, cfrag(sl, j, lane), acc);
        }
        if (c == 1) {
          int nn = 64 * rw8 + 16 * i + l15;
#pragma unroll
          for (int q = 0; q < 4; ++q) zf[lg * 4 + q][nn] = acc[q] + ba2[i];
        }
      };
      pipe3<8>(src, cons, s0, s1, s2);
    }
    __syncthreads();  // B3

    // ---- softmax * cstar (in place), m -> bufA[512:768] -------------------
    {
      int row = tid >> 5, c0 = tid & 31;
      float v[16]; float mx = -1e30f;
#pragma unroll
      for (int j = 0; j < 16; ++j) { v[j] = zf[row][c0 + 32 * j]; mx = fmaxf(mx, v[j]); }
#pragma unroll
      for (int m = 1; m < 32; m <<= 1) mx = fmaxf(mx, __shfl_xor(mx, m));
      float s = 0.f;
#pragma unroll
      for (int j = 0; j < 16; ++j) { v[j] = __expf(v[j] - mx); s += v[j]; }
#pragma unroll
      for (int m = 1; m < 32; m <<= 1) s += __shfl_xor(s, m);
      float inv = __builtin_amdgcn_rcpf(s);
#pragma unroll
      for (int j = 0; j < 16; ++j) {
        int c = c0 + 32 * j;
        bufA[row][c] = (f16)(v[j] * inv * (float)bufA[row][c]);
      }
      for (int idx = tid; idx < 4096; idx += 512) {
        int r = idx >> 8, c = idx & 255;
        bufA[r][512 + c] = (f16)mS[r][c];
      }
    }
    __syncthreads();  // B4

    // ---- stage6: 2 ghid tiles (K=768) + attn2 L1 (K=512), one chain -------
    {
      f32x4 acc = (f32x4){0.f, 0.f, 0.f, 0.f};
      auto src = [&](int ck) -> const f16* {
        if (ck < 24) {
          int T = ck / 12, c = ck % 12;
          return A.W_g1 + (size_t)(16 * (2 * rw8 + T) + l15) * 768 + 64 * c + 8 * lg;
        } else {
          int c = ck - 24;
          return A.W_b1 + (size_t)(16 * rw8 + l15) * 512 + 64 * c + 8 * lg;
        }
      };
      auto cons = [&](int ck, f16* sl) {
        if (ck < 24) {
          int T = ck / 12, c = ck % 12;
          if (c == 0) acc = (f32x4){0.f, 0.f, 0.f, 0.f};
#pragma unroll
          for (int j = 0; j < 2; ++j) {
            f16x8 a = *(const f16x8*)(&bufA[l15][8 * lg + 32 * (2 * c + j)]);
            acc = MFMA16(a, cfrag(sl, j, lane), acc);
          }
          if (c == 11) {
            int nn = 16 * (2 * rw8 + T) + l15;
#pragma unroll
            for (int q = 0; q < 4; ++q) ghid16[lg * 4 + q][nn] = (f16)fmaxf(acc[q] + gb[T], 0.f);
          }
        } else {
          int c = ck - 24;
          if (c == 0) acc = (f32x4){0.f, 0.f, 0.f, 0.f};
#pragma unroll
          for (int j = 0; j < 2; ++j) {
            f16x8 a = *(const f16x8*)(&bufA[l15][8 * lg + 32 * (2 * c + j)]);
            acc = MFMA16(a, cfrag(sl, j, lane), acc);
          }
          if (c == 7) {
            int n = 16 * rw8 + l15;
#pragma unroll
            for (int q = 0; q < 4; ++q) hid16[lg * 4 + q][n] = (f16)fmaxf(acc[q] + b_b1, 0.f);
          }
        }
      };
      pipe3<32>(src, cons, s0, s1, s2);
    }
    __syncthreads();  // B5

    // ---- stage7: attn2 L2 + g1/g2 second layers + m-update, staged --------
    {
      f32x4 acc = (f32x4){0.f,0.f,0.f,0.f};
      f32x4 accB = (f32x4){0.f,0.f,0.f,0.f};
      f32x4 acc1 = (f32x4){0.f,0.f,0.f,0.f};
      auto src = [&](int ck) -> const f16* {
        int i = ck / 6, r = ck % 6, m = r >> 1, c = r & 1;
        int n = 32 * rw8 + 16 * i + l15;
        const f16* base = (m == 0) ? (A.W_b2 + (size_t)n * 128)
                        : (m == 1) ? (A.W_g2 + (size_t)n * 128)
                                   : (A.W_g2 + (size_t)(256 + n) * 128);
        return base + 64 * c + 8 * lg;
      };
      auto cons = [&](int ck, f16* sl) {
        int i = ck / 6, r = ck % 6, m = r >> 1, c = r & 1;
        if (c == 0) acc = (f32x4){0.f, 0.f, 0.f, 0.f};
#pragma unroll
        for (int j = 0; j < 2; ++j) {
          int k = 2 * c + j;
          f16x8 a = (m == 0) ? *(const f16x8*)(&hid16[l15][8 * lg + 32 * k])
                  : (m == 1) ? *(const f16x8*)(&ghid16[l15][8 * lg + 32 * k])
                             : *(const f16x8*)(&ghid16[l15][128 + 8 * lg + 32 * k]);
          acc = MFMA16(a, cfrag(sl, j, lane), acc);
        }
        if (c == 1) {
          if (m == 0) accB = acc;
          else if (m == 1) acc1 = acc;
          else {
            int n = 32 * rw8 + 16 * i + l15;
#pragma unroll
            for (int q = 0; q < 4; ++q) {
              int row = lg * 4 + q;
              float ch = ftanh(accB[q] + bB2[i]);
              float g1 = sigm(acc1[q] + bG1[i]);
              float g2 = sigm(acc[q] + bG2[i]);
              mS[row][n] = g1 * mS[row][n] + g2 * ch;
            }
          }
        }
      };
      pipe3<12>(src, cons, s0, s1, s2);
    }
    __syncthreads();  // B6 (loop end)
  }

  if (last) {
    // ---- output head (VGPR path, once) -----------------------------------
    for (int idx = tid; idx < 4096; idx += 512) {
      int r = idx >> 8, c = idx & 255;
      bufA[r][c] = h16[r][c];
      bufA[r][256 + c] = (f16)mS[r][c];
    }
    __syncthreads();
    {
      int n = 16 * wid;
      f32x4 acc = fc_tileB<16, 808>(bufA, 0, A.W_o1 + (size_t)(n + l15) * 512 + 8 * lg, l15, lg);
      float b = A.ob1[n + l15];
#pragma unroll
      for (int q = 0; q < 4; ++q) hid16[lg * 4 + q][n + l15] = (f16)fmaxf(acc[q] + b, 0.f);
    }
    __syncthreads();
    {
      int row = tid >> 5, c0 = tid & 31;
      float s = 0.f;
#pragma unroll
      for (int j = 0; j < 4; ++j) { int k = c0 + 32 * j; s += (float)hid16[row][k] * A.oW2[k]; }
#pragma unroll
      for (int m = 1; m < 32; m <<= 1) s += __shfl_xor(s, m);
      if (c0 == 0) A.out[r0 + row] = s + A.ob2[0];
    }
  } else {
    for (int idx = tid; idx < 4096; idx += 512) {
      int r = idx >> 8, c = idx & 255;
      size_t g = (size_t)(r0 + r) * 256 + c;
      A.Hst[g] = h16[r][c];
      A.Cst[g] = cS[r][c];
      A.Mst[g] = mS[r][c];
    }
  }
}

extern "C" void kernel_launch(void* const* d_in, const int* in_sizes, int n_in,
                              void* d_out, int out_size, void* d_ws, size_t ws_size,
                              hipStream_t stream) {
  (void)in_sizes; (void)n_in; (void)out_size;
  char* w = (char*)d_ws;
  f16* Wg_t = (f16*)(w + 0);
  f16* Wg_a = (f16*)(w + 458752);
  f16* Wg_v = (f16*)(w + 540672);
  f16* W_a1 = (f16*)(w + 770048);
  f16* W_a2 = (f16*)(w + 901120);
  f16* W_b1 = (f16*)(w + 1032192);
  f16* W_b2 = (f16*)(w + 1163264);
  f16* W_g1 = (f16*)(w + 1228800);
  f16* W_g2 = (f16*)(w + 1622016);
  f16* W_o1 = (f16*)(w + 1753088);
  float* bg = (float*)(w + 1884160);
  f16* Hst = (f16*)(w + 1888256);
  float* Cst = (float*)(w + 3985408);
  float* Mst = (float*)(w + 8179712);
  f16* zx = (f16*)(w + 12374016);

  size_t avail = (ws_size > 12374016) ? ws_size - 12374016 : 0;
  const size_t per_step = (size_t)4096 * 1024 * 2;
  int cs = 1;
  const int divs[6] = {20, 10, 5, 4, 2, 1};
  for (int i = 0; i < 6; ++i)
    if ((size_t)divs[i] * per_step <= avail) { cs = divs[i]; break; }

  PackArgs pa;
  pa.t_Wih = (const float*)d_in[5];  pa.t_Whh = (const float*)d_in[6];  pa.t_b = (const float*)d_in[7];
  pa.a_Wih = (const float*)d_in[8];  pa.a_Whh = (const float*)d_in[9];  pa.a_b = (const float*)d_in[10];
  pa.v_Wih = (const float*)d_in[11]; pa.v_Whh = (const float*)d_in[12]; pa.v_b = (const float*)d_in[13];
  pa.aW1 = (const float*)d_in[14];  pa.aW2 = (const float*)d_in[16];
  pa.bW1 = (const float*)d_in[18];  pa.bW2 = (const float*)d_in[20];
  pa.g1W1 = (const float*)d_in[22]; pa.g2W1 = (const float*)d_in[26];
  pa.g1W2 = (const float*)d_in[24]; pa.g2W2 = (const float*)d_in[28];
  pa.oW1 = (const float*)d_in[30];
  pa.Wg_t = Wg_t; pa.Wg_a = Wg_a; pa.Wg_v = Wg_v; pa.W_a1 = W_a1; pa.W_a2 = W_a2;
  pa.W_b1 = W_b1; pa.W_b2 = W_b2; pa.W_g1 = W_g1; pa.W_g2 = W_g2; pa.W_o1 = W_o1;
  pa.bg = bg;
  pack_w<<<3684, 256, 0, stream>>>(pa);

  MainArgs ma;
  ma.x_p = (const float*)d_in[0];
  ma.c_t = (const float*)d_in[1]; ma.c_a = (const float*)d_in[2]; ma.c_v = (const float*)d_in[3];
  ma.mem0 = (const float*)d_in[4];
  ma.Wg_t = Wg_t; ma.Wg_a = Wg_a; ma.Wg_v = Wg_v; ma.W_a1 = W_a1; ma.W_a2 = W_a2;
  ma.W_b1 = W_b1; ma.W_b2 = W_b2; ma.W_g1 = W_g1; ma.W_g2 = W_g2; ma.W_o1 = W_o1;
  ma.bg = bg;
  ma.a1b1 = (const float*)d_in[15]; ma.a1b2 = (const float*)d_in[17];
  ma.a2b1 = (const float*)d_in[19]; ma.a2b2 = (const float*)d_in[21];
  ma.g1b1 = (const float*)d_in[23]; ma.g1b2 = (const float*)d_in[25];
  ma.g2b1 = (const float*)d_in[27]; ma.g2b2 = (const float*)d_in[29];
  ma.ob1 = (const float*)d_in[31]; ma.oW2 = (const float*)d_in[32]; ma.ob2 = (const float*)d_in[33];
  ma.Hst = Hst; ma.Cst = Cst; ma.Mst = Mst; ma.zx = zx;
  ma.out = (float*)d_out;

  for (int t0 = 0; t0 < 20; t0 += cs) {
    ZxArgs za; za.x = (const float*)d_in[0];
    za.Wg_t = Wg_t; za.Wg_a = Wg_a; za.Wg_v = Wg_v; za.zx = zx; za.t0 = t0;
    gemm_zx<<<dim3(cs * 128), 512, 0, stream>>>(za);
    fused_seq<<<256, 512, 0, stream>>>(ma, cs, t0 == 0 ? 1 : 0,
                                       (t0 + cs >= 20) ? 1 : 0);
  }
}

// Round 15
// 540.764 us; speedup vs baseline: 2.6489x; 2.6489x over previous
//
#include <hip/hip_runtime.h>
#include <math.h>

typedef _Float16 f16;
typedef f16 f16x4 __attribute__((ext_vector_type(4)));
typedef f16 f16x8 __attribute__((ext_vector_type(8)));
typedef float f32x4 __attribute__((ext_vector_type(4)));

#define MFMA16(a, b, c) __builtin_amdgcn_mfma_f32_16x16x32_f16((a), (b), (c), 0, 0, 0)

// ---------------------------------------------------------------------------
// ws layout (bytes) — ALL weights fragment-major: W'[tile][ks][lane][8] with
// value = W[tile*16 + (lane&15)][32*ks + 8*(lane>>4) + j]  (bit-identical
// per-lane data to the old row-major reads; wave loads are now contiguous).
//  Wx_t  [32][10][512] @ 0        (t_Wih cols 0:300 pad 320)
//  Wx_a  [16][3][512]  @ 327680   (a_Wih cols 0:81 pad 96)
//  Wx_v  [16][12][512] @ 376832   (v_Wih cols 0:371 pad 384)
//  Wh_t  [32][4][512]  @ 573440   (t_Whh, K=128)
//  Wh_a  [16][2][512]  @ 704512   (a_Whh, K=64)
//  Wh_v  [16][2][512]  @ 737280   (v_Whh, K=64)
//  W_a1  [8][16][512]  @ 770048   W_a2 [32][4][512] @ 901120
//  W_b1  [8][16][512]  @ 1032192  W_b2 [16][4][512] @ 1163264
//  W_g1  [16][24][512] @ 1228800  (tiles 0-7 g1_W1, 8-15 g2_W1)
//  W_g2  [32][4][512]  @ 1622016  (tiles 0-15 g1_W2, 16-31 g2_W2)
//  W_o1  [8][16][512]  @ 1753088
//  bg f32[1024] @ 1884160 (gate bias, interleaved n=4u+g)
//  Hst f16[4096][256]@1888256  Cst f32@3985408  Mst f32@8179712
//  zx  f16[cs*4096][1024]@12374016
// Gate rows stay interleaved n=4u+g (srow=(n&3)*H + (n>>2)).
// ---------------------------------------------------------------------------

struct PackArgs {
  const float *t_Wih, *t_Whh, *t_b, *a_Wih, *a_Whh, *a_b, *v_Wih, *v_Whh, *v_b;
  const float *aW1, *aW2, *bW1, *bW2, *g1W1, *g2W1, *g1W2, *g2W2, *oW1;
  f16 *Wx_t, *Wx_a, *Wx_v, *Wh_t, *Wh_a, *Wh_v;
  f16 *W_a1, *W_a2, *W_b1, *W_b2, *W_g1, *W_g2, *W_o1;
  float *bg;
};

__device__ __forceinline__ void fdec(int e, int NK, int& row, int& col) {
  int t = e / (NK * 512);
  int r = e % (NK * 512);
  int ks = r >> 9;
  int lane = (r & 511) >> 3;
  int j = r & 7;
  row = t * 16 + (lane & 15);
  col = 32 * ks + 8 * (lane >> 4) + j;
}

__global__ __launch_bounds__(256) void pack_w(PackArgs p) {
  int idx = blockIdx.x * 256 + threadIdx.x;
  int row, col;
  if (idx < 163840) {  // Wx_t [32][10]
    fdec(idx, 10, row, col);
    int srow = (row & 3) * 128 + (row >> 2);
    p.Wx_t[idx] = (f16)((col < 300) ? p.t_Wih[srow * 300 + col] : 0.f);
    return;
  }
  idx -= 163840;
  if (idx < 24576) {  // Wx_a [16][3]
    fdec(idx, 3, row, col);
    int srow = (row & 3) * 64 + (row >> 2);
    p.Wx_a[idx] = (f16)((col < 81) ? p.a_Wih[srow * 81 + col] : 0.f);
    return;
  }
  idx -= 24576;
  if (idx < 98304) {  // Wx_v [16][12]
    fdec(idx, 12, row, col);
    int srow = (row & 3) * 64 + (row >> 2);
    p.Wx_v[idx] = (f16)((col < 371) ? p.v_Wih[srow * 371 + col] : 0.f);
    return;
  }
  idx -= 98304;
  if (idx < 65536) {  // Wh_t [32][4], K=128
    fdec(idx, 4, row, col);
    int srow = (row & 3) * 128 + (row >> 2);
    p.Wh_t[idx] = (f16)p.t_Whh[srow * 128 + col];
    return;
  }
  idx -= 65536;
  if (idx < 16384) {  // Wh_a [16][2], K=64
    fdec(idx, 2, row, col);
    int srow = (row & 3) * 64 + (row >> 2);
    p.Wh_a[idx] = (f16)p.a_Whh[srow * 64 + col];
    return;
  }
  idx -= 16384;
  if (idx < 16384) {  // Wh_v [16][2]
    fdec(idx, 2, row, col);
    int srow = (row & 3) * 64 + (row >> 2);
    p.Wh_v[idx] = (f16)p.v_Whh[srow * 64 + col];
    return;
  }
  idx -= 16384;
  if (idx < 65536) { fdec(idx, 16, row, col); p.W_a1[idx] = (f16)p.aW1[row * 512 + col]; return; }
  idx -= 65536;
  if (idx < 65536) { fdec(idx, 4, row, col); p.W_a2[idx] = (f16)p.aW2[row * 128 + col]; return; }
  idx -= 65536;
  if (idx < 65536) { fdec(idx, 16, row, col); p.W_b1[idx] = (f16)p.bW1[row * 512 + col]; return; }
  idx -= 65536;
  if (idx < 32768) { fdec(idx, 4, row, col); p.W_b2[idx] = (f16)p.bW2[row * 128 + col]; return; }
  idx -= 32768;
  if (idx < 196608) {  // W_g1 [16][24]
    fdec(idx, 24, row, col);
    p.W_g1[idx] = (f16)((row < 128) ? p.g1W1[row * 768 + col] : p.g2W1[(row - 128) * 768 + col]);
    return;
  }
  idx -= 196608;
  if (idx < 65536) {  // W_g2 [32][4]
    fdec(idx, 4, row, col);
    p.W_g2[idx] = (f16)((row < 256) ? p.g1W2[row * 128 + col] : p.g2W2[(row - 256) * 128 + col]);
    return;
  }
  idx -= 65536;
  if (idx < 65536) { fdec(idx, 16, row, col); p.W_o1[idx] = (f16)p.oW1[row * 512 + col]; return; }
  idx -= 65536;
  if (idx < 1024) {
    int n = idx;
    float v;
    if (n < 512)      v = p.t_b[(n & 3) * 128 + (n >> 2)];
    else if (n < 768) { int m = n - 512; v = p.a_b[(m & 3) * 64 + (m >> 2)]; }
    else              { int m = n - 768; v = p.v_b[(m & 3) * 64 + (m >> 2)]; }
    p.bg[n] = v;
  }
}

// ===========================================================================
// zx GEMM: 32-row blocks, x staged once into LDS; fragment-major weights
// (contiguous 1KB wave loads).
// ===========================================================================
struct ZxArgs { const float* x; const f16 *Wx_t, *Wx_a, *Wx_v; f16* zx; int t0; };

template <int KS, int XOFF>
__device__ __forceinline__ void zx_wave(const f16* __restrict__ Wx, int nt0, int n0g,
                                        const f16 (*Xs)[808], f16* __restrict__ zx,
                                        int mloc, int lane, int l15, int lg) {
#pragma unroll 1
  for (int half = 0; half < 2; ++half) {
    f32x4 acc[8];
#pragma unroll
    for (int j = 0; j < 8; ++j) acc[j] = (f32x4){0.f, 0.f, 0.f, 0.f};
#pragma unroll 1
    for (int ks = 0; ks < KS; ++ks) {
      f16x8 w[4];
#pragma unroll
      for (int i = 0; i < 4; ++i)
        w[i] = *(const f16x8*)(Wx + (size_t)((nt0 + 4 * half + i) * KS + ks) * 512 + lane * 8);
      f16x8 a0 = *(const f16x8*)(&Xs[l15][XOFF + 32 * ks + 8 * lg]);
      f16x8 a1 = *(const f16x8*)(&Xs[16 + l15][XOFF + 32 * ks + 8 * lg]);
#pragma unroll
      for (int i = 0; i < 4; ++i) {
        acc[i] = MFMA16(a0, w[i], acc[i]);
        acc[4 + i] = MFMA16(a1, w[i], acc[4 + i]);
      }
    }
#pragma unroll
    for (int mt = 0; mt < 2; ++mt)
#pragma unroll
      for (int i = 0; i < 4; ++i) {
        int ng = n0g + 64 * half + 16 * i + l15;
#pragma unroll
        for (int q = 0; q < 4; ++q)
          zx[(size_t)(mloc + mt * 16 + 4 * lg + q) * 1024 + ng] = (f16)acc[mt * 4 + i][q];
      }
  }
}

__global__ __launch_bounds__(512, 2) void gemm_zx(ZxArgs z) {
  __shared__ f16 Xs[32][808];
  const int tid = threadIdx.x, wid = tid >> 6, lane = tid & 63, l15 = lane & 15, lg = lane >> 4;
  const int mloc = blockIdx.x * 32;
  {
    int r = tid >> 4;
    const float* xr = z.x + ((size_t)z.t0 * 4096 + mloc + r) * 752;
    for (int c = tid & 15; c < 800; c += 16) {
      float v;
      if (c < 320)      v = (c < 300) ? xr[c] : 0.f;
      else if (c < 416) { int s = c - 320; v = (s < 81) ? xr[300 + s] : 0.f; }
      else              { int s = c - 416; v = (s < 371) ? xr[381 + s] : 0.f; }
      Xs[r][c] = (f16)v;
    }
  }
  __syncthreads();
  if (wid < 4)
    zx_wave<10, 0>(z.Wx_t, 8 * wid, 128 * wid, Xs, z.zx, mloc, lane, l15, lg);
  else if (wid < 6)
    zx_wave<3, 320>(z.Wx_a, 8 * (wid - 4), 512 + 128 * (wid - 4), Xs, z.zx, mloc, lane, l15, lg);
  else
    zx_wave<12, 416>(z.Wx_v, 8 * (wid - 6), 768 + 128 * (wid - 6), Xs, z.zx, mloc, lane, l15, lg);
}

// ===========================================================================
// Recurrent kernel — R13 structure, fragment-major weights.
// ===========================================================================
struct MainArgs {
  const float *x_p, *c_t, *c_a, *c_v, *mem0;
  const f16 *Wh_t, *Wh_a, *Wh_v, *W_a1, *W_a2, *W_b1, *W_b2, *W_g1, *W_g2, *W_o1;
  const float *bg, *a1b1, *a1b2, *a2b1, *a2b2, *g1b1, *g1b2, *g2b1, *g2b2, *ob1, *oW2, *ob2;
  f16 *Hst; float *Cst, *Mst; const f16 *zx;
  float *out;
};

__device__ __forceinline__ float sigm(float x) {
  return __builtin_amdgcn_rcpf(1.f + __expf(-x));
}
__device__ __forceinline__ float ftanh(float x) {
  float t = __expf(-2.f * fabsf(x));
  float r = (1.f - t) * __builtin_amdgcn_rcpf(1.f + t);
  return copysignf(r, x);
}

// ---- fragment-major fc tile: wave loads contiguous 1KB; groups of <=8 ------
template <int KS, int LDA>
__device__ __forceinline__ f32x4 fc_tileF(const f16 (*Asrc)[LDA], int acol,
                                          const f16* Wtile, int lane, int l15, int lg) {
  f32x4 acc = {0.f, 0.f, 0.f, 0.f};
  constexpr int GB = (KS < 8) ? KS : 8;
  constexpr int G = (KS + GB - 1) / GB;
#pragma unroll
  for (int g = 0; g < G; ++g) {
    f16x8 w[GB];
#pragma unroll
    for (int j = 0; j < GB; ++j)
      w[j] = *(const f16x8*)(Wtile + (size_t)(g * GB + j) * 512 + lane * 8);
#pragma unroll
    for (int j = 0; j < GB; ++j) {
      f16x8 a = *(const f16x8*)(&Asrc[l15][acol + 8 * lg + 32 * (g * GB + j)]);
      acc = MFMA16(a, w[j], acc);
    }
  }
  return acc;
}

// ---- gate GEMM (h-part), 4 tile-pairs, fragment-major weights --------------
template <int KSH>
__device__ __forceinline__ void gmm_zxB(const f16* Wh, const float* bg, const f16* zxr,
                                        int nc0, int n0, int cub,
                                        int l15, int lg, int hb, int lane,
                                        const f16 (*hc)[264], f16 (*hn)[264],
                                        float (*cS)[260], f16 (*bufA)[808]) {
  f16x8 ah[KSH];
#pragma unroll
  for (int k = 0; k < KSH; ++k)
    ah[k] = *(const f16x8*)(&hc[l15][hb + 8 * lg + 32 * k]);
#pragma unroll 1
  for (int p = 0; p < 4; ++p) {
    const int tau = (nc0 >> 4) + 2 * p;
    f16x8 w0[KSH], w1[KSH];
#pragma unroll
    for (int k = 0; k < KSH; ++k) {
      w0[k] = *(const f16x8*)(Wh + (size_t)(tau * KSH + k) * 512 + lane * 8);
      w1[k] = *(const f16x8*)(Wh + (size_t)((tau + 1) * KSH + k) * 512 + lane * 8);
    }
    f16x4 z0 = *(const f16x4*)(zxr + n0 + 32 * p + 4 * lg);
    f16x4 z1 = *(const f16x4*)(zxr + n0 + 32 * p + 16 + 4 * lg);
    f32x4 a0 = {0.f, 0.f, 0.f, 0.f}, a1 = {0.f, 0.f, 0.f, 0.f};
#pragma unroll
    for (int k = 0; k < KSH; ++k) {
      a0 = MFMA16(w0[k], ah[k], a0);
      a1 = MFMA16(w1[k], ah[k], a1);
    }
    const float4 b0 = *(const float4*)&bg[n0 + 32 * p + 4 * lg];
    const float4 b1 = *(const float4*)&bg[n0 + 32 * p + 16 + 4 * lg];
    {
      float gi = sigm(a0[0] + (float)z0[0] + b0.x);
      float gf = sigm(a0[1] + (float)z0[1] + b0.y);
      float gg = ftanh(a0[2] + (float)z0[2] + b0.z);
      float go = sigm(a0[3] + (float)z0[3] + b0.w);
      int cu = cub + ((nc0 + 32 * p) >> 2) + lg;
      float cold = cS[l15][cu];
      float cnew = gf * cold + gi * gg;
      cS[l15][cu] = cnew;
      hn[l15][cu] = (f16)(go * ftanh(cnew));
      bufA[l15][cu] = (f16)cold;        // c_star = [pre_c | cur_c]
      bufA[l15][256 + cu] = (f16)cnew;
    }
    {
      float gi = sigm(a1[0] + (float)z1[0] + b1.x);
      float gf = sigm(a1[1] + (float)z1[1] + b1.y);
      float gg = ftanh(a1[2] + (float)z1[2] + b1.z);
      float go = sigm(a1[3] + (float)z1[3] + b1.w);
      int cu = cub + ((nc0 + 32 * p + 16) >> 2) + lg;
      float cold = cS[l15][cu];
      float cnew = gf * cold + gi * gg;
      cS[l15][cu] = cnew;
      hn[l15][cu] = (f16)(go * ftanh(cnew));
      bufA[l15][cu] = (f16)cold;
      bufA[l15][256 + cu] = (f16)cnew;
    }
  }
}

__global__ __launch_bounds__(512, 2) void fused_seq(MainArgs A, int cs,
                                                    int first, int last) {
  __shared__ f16  h16a[16][264];    // h double-buffer
  __shared__ f16  h16b[16][264];
  __shared__ float cS[16][260];
  __shared__ float mS[16][260];
  __shared__ f16  bufA[16][808];    // cstar/attended (0:512) | m fp16 (512:768)
  __shared__ f16  hid16[16][264];
  __shared__ f16  ghid16[16][264];
  __shared__ float zf[16][516];

  const int tid = threadIdx.x;
  const int wid = tid >> 6, lane = tid & 63, l15 = lane & 15, lg = lane >> 4;
  const int r0 = blockIdx.x * 16;

  f16 (*hc)[264] = h16a;
  f16 (*hn)[264] = h16b;

  if (first) {
    for (int idx = tid; idx < 4096; idx += 512) {
      int r = idx >> 8, c = idx & 255, R = r0 + r;
      h16a[r][c] = (f16)0.f;
      float cv = (c < 128) ? A.c_t[R * 128 + c]
                           : (c < 192 ? A.c_a[R * 64 + c - 128] : A.c_v[R * 64 + c - 192]);
      cS[r][c] = cv;
      mS[r][c] = A.mem0[R * 256 + c];
    }
  } else {
    for (int idx = tid; idx < 4096; idx += 512) {
      int r = idx >> 8, c = idx & 255;
      size_t g = (size_t)(r0 + r) * 256 + c;
      h16a[r][c] = A.Hst[g];
      cS[r][c] = A.Cst[g];
      mS[r][c] = A.Mst[g];
    }
  }
  __syncthreads();

#pragma unroll 1
  for (int ts = 0; ts < cs; ++ts) {
    // ============== gates (h double-buffered: no pre-barrier) ==============
    {
      const f16* zxr = A.zx + ((size_t)ts * 4096 + r0 + l15) * 1024;
      if (wid < 4)
        gmm_zxB<4>(A.Wh_t, A.bg, zxr, 128 * wid, 128 * wid, 0,
                   l15, lg, 0, lane, hc, hn, cS, bufA);
      else if (wid < 6)
        gmm_zxB<2>(A.Wh_a, A.bg, zxr, 128 * (wid - 4), 512 + 128 * (wid - 4), 128,
                   l15, lg, 128, lane, hc, hn, cS, bufA);
      else
        gmm_zxB<2>(A.Wh_v, A.bg, zxr, 128 * (wid - 6), 768 + 128 * (wid - 6), 192,
                   l15, lg, 192, lane, hc, hn, cS, bufA);
    }
    __syncthreads();  // B1: bufA complete

    // ============== attn1 L1: hid = relu(cstar @ W^T + b) ==================
    {
      int n = 16 * wid;
      f32x4 acc = fc_tileF<16, 808>(bufA, 0, A.W_a1 + (size_t)wid * 16 * 512, lane, l15, lg);
      float b = A.a1b1[n + l15];
#pragma unroll
      for (int q = 0; q < 4; ++q) hid16[lg * 4 + q][n + l15] = (f16)fmaxf(acc[q] + b, 0.f);
    }
    __syncthreads();  // B2

    // ============== attn1 L2: logits, 4 tiles/wave =========================
    {
#pragma unroll
      for (int i = 0; i < 4; ++i) {
        int tt = 4 * wid + i;
        int n = 16 * tt + l15;
        f32x4 acc = fc_tileF<4, 264>(hid16, 0, A.W_a2 + (size_t)tt * 4 * 512, lane, l15, lg);
        float b = A.a1b2[n];
#pragma unroll
        for (int q = 0; q < 4; ++q) zf[lg * 4 + q][n] = acc[q] + b;
      }
    }
    __syncthreads();  // B3

    // ============== softmax * cstar (in place), m -> bufA[512:768] =========
    {
      int row = tid >> 5, c0 = tid & 31;
      float v[16]; float mx = -1e30f;
#pragma unroll
      for (int j = 0; j < 16; ++j) { v[j] = zf[row][c0 + 32 * j]; mx = fmaxf(mx, v[j]); }
#pragma unroll
      for (int m = 1; m < 32; m <<= 1) mx = fmaxf(mx, __shfl_xor(mx, m));
      float s = 0.f;
#pragma unroll
      for (int j = 0; j < 16; ++j) { v[j] = __expf(v[j] - mx); s += v[j]; }
#pragma unroll
      for (int m = 1; m < 32; m <<= 1) s += __shfl_xor(s, m);
      float inv = __builtin_amdgcn_rcpf(s);
#pragma unroll
      for (int j = 0; j < 16; ++j) {
        int c = c0 + 32 * j;
        bufA[row][c] = (f16)(v[j] * inv * (float)bufA[row][c]);
      }
      for (int idx = tid; idx < 4096; idx += 512) {
        int r = idx >> 8, c = idx & 255;
        bufA[r][512 + c] = (f16)mS[r][c];
      }
    }
    __syncthreads();  // B4

    // ====== stage 6: every wave 2 ghid tiles + 1 attn2L1 tile ==============
    {
#pragma unroll 1
      for (int i = 0; i < 2; ++i) {
        int tt = 2 * wid + i;
        int nn = 16 * tt + l15;
        f32x4 acc = fc_tileF<24, 808>(bufA, 0, A.W_g1 + (size_t)tt * 24 * 512, lane, l15, lg);
        float b = (nn < 128) ? A.g1b1[nn] : A.g2b1[nn - 128];
#pragma unroll
        for (int q = 0; q < 4; ++q) ghid16[lg * 4 + q][nn] = (f16)fmaxf(acc[q] + b, 0.f);
      }
      {
        int n = 16 * wid;
        f32x4 acc = fc_tileF<16, 808>(bufA, 0, A.W_b1 + (size_t)wid * 16 * 512, lane, l15, lg);
        float b = A.a2b1[n + l15];
#pragma unroll
        for (int q = 0; q < 4; ++q) hid16[lg * 4 + q][n + l15] = (f16)fmaxf(acc[q] + b, 0.f);
      }
    }
    __syncthreads();  // B5

    // ====== stage 7: attn2 L2 + g1/g2 second layers + m-update =============
    {
#pragma unroll 1
      for (int i = 0; i < 2; ++i) {
        int tt = 2 * wid + i;            // 16-tile index
        int n = 16 * tt + l15;
        f16x8 wB[4], w1[4], w2[4];
#pragma unroll
        for (int k = 0; k < 4; ++k) {
          wB[k] = *(const f16x8*)(A.W_b2 + (size_t)(tt * 4 + k) * 512 + lane * 8);
          w1[k] = *(const f16x8*)(A.W_g2 + (size_t)(tt * 4 + k) * 512 + lane * 8);
          w2[k] = *(const f16x8*)(A.W_g2 + (size_t)((16 + tt) * 4 + k) * 512 + lane * 8);
        }
        f32x4 acB = {0.f, 0.f, 0.f, 0.f};
        f32x4 ac1 = {0.f, 0.f, 0.f, 0.f};
        f32x4 ac2 = {0.f, 0.f, 0.f, 0.f};
#pragma unroll
        for (int k = 0; k < 4; ++k) {
          f16x8 ha = *(const f16x8*)(&hid16[l15][8 * lg + 32 * k]);
          f16x8 ga1 = *(const f16x8*)(&ghid16[l15][8 * lg + 32 * k]);
          f16x8 ga2 = *(const f16x8*)(&ghid16[l15][128 + 8 * lg + 32 * k]);
          acB = MFMA16(ha, wB[k], acB);
          ac1 = MFMA16(ga1, w1[k], ac1);
          ac2 = MFMA16(ga2, w2[k], ac2);
        }
        float bB = A.a2b2[n], b1 = A.g1b2[n], b2 = A.g2b2[n];
#pragma unroll
        for (int q = 0; q < 4; ++q) {
          int row = lg * 4 + q;
          float ch = ftanh(acB[q] + bB);
          float g1 = sigm(ac1[q] + b1);
          float g2 = sigm(ac2[q] + b2);
          mS[row][n] = g1 * mS[row][n] + g2 * ch;
        }
      }
    }
    __syncthreads();  // B6 (loop end)

    { f16 (*tmp)[264] = hc; hc = hn; hn = tmp; }
  }

  if (last) {
    // ============== output head ===========================================
    for (int idx = tid; idx < 4096; idx += 512) {
      int r = idx >> 8, c = idx & 255;
      bufA[r][c] = hc[r][c];
      bufA[r][256 + c] = (f16)mS[r][c];
    }
    __syncthreads();
    {
      int n = 16 * wid;
      f32x4 acc = fc_tileF<16, 808>(bufA, 0, A.W_o1 + (size_t)wid * 16 * 512, lane, l15, lg);
      float b = A.ob1[n + l15];
#pragma unroll
      for (int q = 0; q < 4; ++q) hid16[lg * 4 + q][n + l15] = (f16)fmaxf(acc[q] + b, 0.f);
    }
    __syncthreads();
    {
      int row = tid >> 5, c0 = tid & 31;
      float s = 0.f;
#pragma unroll
      for (int j = 0; j < 4; ++j) { int k = c0 + 32 * j; s += (float)hid16[row][k] * A.oW2[k]; }
#pragma unroll
      for (int m = 1; m < 32; m <<= 1) s += __shfl_xor(s, m);
      if (c0 == 0) A.out[r0 + row] = s + A.ob2[0];
    }
  } else {
    for (int idx = tid; idx < 4096; idx += 512) {
      int r = idx >> 8, c = idx & 255;
      size_t g = (size_t)(r0 + r) * 256 + c;
      A.Hst[g] = hc[r][c];
      A.Cst[g] = cS[r][c];
      A.Mst[g] = mS[r][c];
    }
  }
}

extern "C" void kernel_launch(void* const* d_in, const int* in_sizes, int n_in,
                              void* d_out, int out_size, void* d_ws, size_t ws_size,
                              hipStream_t stream) {
  (void)in_sizes; (void)n_in; (void)out_size;
  char* w = (char*)d_ws;
  f16* Wx_t = (f16*)(w + 0);
  f16* Wx_a = (f16*)(w + 327680);
  f16* Wx_v = (f16*)(w + 376832);
  f16* Wh_t = (f16*)(w + 573440);
  f16* Wh_a = (f16*)(w + 704512);
  f16* Wh_v = (f16*)(w + 737280);
  f16* W_a1 = (f16*)(w + 770048);
  f16* W_a2 = (f16*)(w + 901120);
  f16* W_b1 = (f16*)(w + 1032192);
  f16* W_b2 = (f16*)(w + 1163264);
  f16* W_g1 = (f16*)(w + 1228800);
  f16* W_g2 = (f16*)(w + 1622016);
  f16* W_o1 = (f16*)(w + 1753088);
  float* bg = (float*)(w + 1884160);
  f16* Hst = (f16*)(w + 1888256);
  float* Cst = (float*)(w + 3985408);
  float* Mst = (float*)(w + 8179712);
  f16* zx = (f16*)(w + 12374016);

  size_t avail = (ws_size > 12374016) ? ws_size - 12374016 : 0;
  const size_t per_step = (size_t)4096 * 1024 * 2;
  int cs = 1;
  const int divs[6] = {20, 10, 5, 4, 2, 1};
  for (int i = 0; i < 6; ++i)
    if ((size_t)divs[i] * per_step <= avail) { cs = divs[i]; break; }

  PackArgs pa;
  pa.t_Wih = (const float*)d_in[5];  pa.t_Whh = (const float*)d_in[6];  pa.t_b = (const float*)d_in[7];
  pa.a_Wih = (const float*)d_in[8];  pa.a_Whh = (const float*)d_in[9];  pa.a_b = (const float*)d_in[10];
  pa.v_Wih = (const float*)d_in[11]; pa.v_Whh = (const float*)d_in[12]; pa.v_b = (const float*)d_in[13];
  pa.aW1 = (const float*)d_in[14];  pa.aW2 = (const float*)d_in[16];
  pa.bW1 = (const float*)d_in[18];  pa.bW2 = (const float*)d_in[20];
  pa.g1W1 = (const float*)d_in[22]; pa.g2W1 = (const float*)d_in[26];
  pa.g1W2 = (const float*)d_in[24]; pa.g2W2 = (const float*)d_in[28];
  pa.oW1 = (const float*)d_in[30];
  pa.Wx_t = Wx_t; pa.Wx_a = Wx_a; pa.Wx_v = Wx_v;
  pa.Wh_t = Wh_t; pa.Wh_a = Wh_a; pa.Wh_v = Wh_v;
  pa.W_a1 = W_a1; pa.W_a2 = W_a2; pa.W_b1 = W_b1; pa.W_b2 = W_b2;
  pa.W_g1 = W_g1; pa.W_g2 = W_g2; pa.W_o1 = W_o1;
  pa.bg = bg;
  pack_w<<<3684, 256, 0, stream>>>(pa);

  MainArgs ma;
  ma.x_p = (const float*)d_in[0];
  ma.c_t = (const float*)d_in[1]; ma.c_a = (const float*)d_in[2]; ma.c_v = (const float*)d_in[3];
  ma.mem0 = (const float*)d_in[4];
  ma.Wh_t = Wh_t; ma.Wh_a = Wh_a; ma.Wh_v = Wh_v;
  ma.W_a1 = W_a1; ma.W_a2 = W_a2; ma.W_b1 = W_b1; ma.W_b2 = W_b2;
  ma.W_g1 = W_g1; ma.W_g2 = W_g2; ma.W_o1 = W_o1;
  ma.bg = bg;
  ma.a1b1 = (const float*)d_in[15]; ma.a1b2 = (const float*)d_in[17];
  ma.a2b1 = (const float*)d_in[19]; ma.a2b2 = (const float*)d_in[21];
  ma.g1b1 = (const float*)d_in[23]; ma.g1b2 = (const float*)d_in[25];
  ma.g2b1 = (const float*)d_in[27]; ma.g2b2 = (const float*)d_in[29];
  ma.ob1 = (const float*)d_in[31]; ma.oW2 = (const float*)d_in[32]; ma.ob2 = (const float*)d_in[33];
  ma.Hst = Hst; ma.Cst = Cst; ma.Mst = Mst; ma.zx = zx;
  ma.out = (float*)d_out;

  for (int t0 = 0; t0 < 20; t0 += cs) {
    ZxArgs za; za.x = (const float*)d_in[0];
    za.Wx_t = Wx_t; za.Wx_a = Wx_a; za.Wx_v = Wx_v; za.zx = zx; za.t0 = t0;
    gemm_zx<<<dim3(cs * 128), 512, 0, stream>>>(za);
    fused_seq<<<256, 512, 0, stream>>>(ma, cs, t0 == 0 ? 1 : 0,
                                       (t0 + cs >= 20) ? 1 : 0);
  }
}